// Round 2
// baseline (309.236 us; speedup 1.0000x reference)
//
#include <hip/hip_runtime.h>

// Problem constants (fixed shapes)
#define BB 8192      // batch
#define DZ 1024
#define DS 64
#define DH 4096
#define KEXT (DH + DS)   // 4160: K of GEMM2 = [H | s]

typedef float floatx4 __attribute__((ext_vector_type(4)));
typedef __bf16 bf16x8 __attribute__((ext_vector_type(8)));
typedef __attribute__((address_space(1))) void* as1_void_ptr;
typedef __attribute__((address_space(3))) void* as3_void_ptr;

__device__ __forceinline__ void async_copy16(const void* g, void* l) {
    // global -> LDS direct copy, 16B per lane; LDS dest = wave-uniform base + lane*16
    __builtin_amdgcn_global_load_lds((as1_void_ptr)g, (as3_void_ptr)l, 16, 0, 0);
}

// ---------------- conversion kernels ----------------

__global__ void cvt_f32_bf16(const float* __restrict__ in, __bf16* __restrict__ out, int n4) {
    int i = blockIdx.x * blockDim.x + threadIdx.x;
    if (i < n4) {
        float4 v = ((const float4*)in)[i];
        __bf16* o = out + (size_t)i * 4;
        o[0] = (__bf16)v.x; o[1] = (__bf16)v.y; o[2] = (__bf16)v.z; o[3] = (__bf16)v.w;
    }
}

// B2b[j, 0:4096] = W2[j, :], B2b[j, 4096:4160] = C[j, :]   (j = 0..1023)
__global__ void build_B2(const float* __restrict__ W2, const float* __restrict__ C,
                         __bf16* __restrict__ B2b) {
    int j = blockIdx.x;
    for (int h = threadIdx.x; h < KEXT; h += 256) {
        float v = (h < DH) ? W2[(size_t)j * DH + h] : C[(size_t)j * DS + (h - DH)];
        B2b[(size_t)j * KEXT + h] = (__bf16)v;
    }
}

// Hb[b, 4096+k] = s[b, k]
__global__ void stage_s(const float* __restrict__ s, __bf16* __restrict__ Hb) {
    int idx = blockIdx.x * 256 + threadIdx.x;   // 0 .. 8192*64-1
    int b = idx >> 6, k = idx & 63;
    Hb[(size_t)b * KEXT + DH + k] = (__bf16)s[idx];
}

// ---------------- GEMM1: Hb[:, :4096] = relu(zb @ W1b^T + h1) ----------------
// NT layout: A = zb [8192 x 1024] (K-major), B = W1b [4096 x 1024] (K-major).
// 128x128 block tile, BK=32, 4 waves each computing 64x64 via 4x4 grid of 16x16x32 MFMA.
// Epilogue staged through LDS (reusing the K-loop buffers) for 16B stores.

__global__ __launch_bounds__(256) void gemm1_relu(
    const __bf16* __restrict__ Ag, const __bf16* __restrict__ Bg,
    const float* __restrict__ h1, __bf16* __restrict__ Hb)
{
    constexpr int K = DZ, ldA = DZ, ldB = DZ;
    __shared__ __align__(16) __bf16 smem[2 * 128 * 32];   // As | Bs, 16 KB
    __bf16* As = smem;
    __bf16* Bs = smem + 128 * 32;

    const int tid = threadIdx.x;
    const int wave = tid >> 6, lane = tid & 63;
    const int wm = wave >> 1, wn = wave & 1;
    const int row0 = blockIdx.x * 128;
    const int col0 = blockIdx.y * 128;

    const __bf16* a0 = Ag + (size_t)(row0 + (tid >> 2)) * ldA + (tid & 3) * 8;
    const __bf16* b0 = Bg + (size_t)(col0 + (tid >> 2)) * ldB + (tid & 3) * 8;
    __bf16* lA = As + wave * 512;   // + lane*8 implicit
    __bf16* lB = Bs + wave * 512;

    const __bf16* Afrag = As + (wm * 64 + (lane & 15)) * 32 + (lane >> 4) * 8;
    const __bf16* Bfrag = Bs + (wn * 64 + (lane & 15)) * 32 + (lane >> 4) * 8;

    floatx4 acc[4][4];
#pragma unroll
    for (int i = 0; i < 4; ++i)
#pragma unroll
        for (int j = 0; j < 4; ++j) acc[i][j] = (floatx4)0.0f;

    for (int kt = 0; kt < K / 32; ++kt) {
        const __bf16* ak = a0 + kt * 32;
        const __bf16* bk = b0 + kt * 32;
        async_copy16(ak,            lA);
        async_copy16(ak + 64 * ldA, lA + 2048);
        async_copy16(bk,            lB);
        async_copy16(bk + 64 * ldB, lB + 2048);
        __builtin_amdgcn_s_waitcnt(0);
        __syncthreads();

        bf16x8 af[4], bfr[4];
#pragma unroll
        for (int i = 0; i < 4; ++i) af[i] = *(const bf16x8*)(Afrag + i * 16 * 32);
#pragma unroll
        for (int j = 0; j < 4; ++j) bfr[j] = *(const bf16x8*)(Bfrag + j * 16 * 32);
#pragma unroll
        for (int i = 0; i < 4; ++i)
#pragma unroll
            for (int j = 0; j < 4; ++j)
                acc[i][j] = __builtin_amdgcn_mfma_f32_16x16x32_bf16(af[i], bfr[j], acc[i][j], 0, 0, 0);
        __syncthreads();
    }

    // ---- epilogue: 4 passes of 32 rows, staged through LDS (pad stride 136) ----
    const int c_m = lane & 15;
    const int q   = lane >> 4;
    float bias[4];
#pragma unroll
    for (int j = 0; j < 4; ++j) bias[j] = h1[col0 + wn * 64 + c_m + j * 16];

    constexpr int CST = 136;   // 128 + 8 pad (keeps 16B alignment: 136*2 = 272 = 16*17)
#pragma unroll
    for (int p = 0; p < 4; ++p) {
        __syncthreads();
        if (wm == (p >> 1)) {
#pragma unroll
            for (int ii = 0; ii < 2; ++ii) {
                const int i = (p & 1) * 2 + ii;
#pragma unroll
                for (int j = 0; j < 4; ++j) {
                    const int c_l = wn * 64 + c_m + j * 16;
#pragma unroll
                    for (int rg = 0; rg < 4; ++rg) {
                        const int r_l = q * 4 + ii * 16 + rg;   // 0..31 within pass
                        float v = acc[i][j][rg] + bias[j];
                        v = v > 0.0f ? v : 0.0f;
                        smem[r_l * CST + c_l] = (__bf16)v;
                    }
                }
            }
        }
        __syncthreads();
        const int rbase = row0 + p * 32;
#pragma unroll
        for (int it = 0; it < 2; ++it) {
            const int idx = it * 256 + tid;          // 0..511 chunks of 8
            const int rr = idx >> 4, cc = (idx & 15) * 8;
            *(bf16x8*)(Hb + (size_t)(rbase + rr) * KEXT + col0 + cc) =
                *(const bf16x8*)(smem + rr * CST + cc);
        }
    }
}

// ---------------- GEMM2: out = Hb @ B2b^T + A*zb + h2 ----------------
// A = Hb [8192 x 4160] (K-major), B = B2b [1024 x 4160] (K-major), K = 4160.
// 64x128 block tile -> 1024 blocks (4/CU). 4 waves; wave w computes all 64 rows
// x cols [w*32, w*32+32) via 4x2 grid of 16x16x32 MFMA.

__global__ __launch_bounds__(256) void gemm2_out(
    const __bf16* __restrict__ Ag, const __bf16* __restrict__ Bg,
    const float* __restrict__ Adiag, const float* __restrict__ h2,
    const __bf16* __restrict__ zb, float* __restrict__ out)
{
    constexpr int K = KEXT, ldA = KEXT, ldB = KEXT;
    __shared__ __align__(16) __bf16 As[64 * 32];    // 4 KB
    __shared__ __align__(16) __bf16 Bs[128 * 32];   // 8 KB

    const int tid = threadIdx.x;
    const int wave = tid >> 6, lane = tid & 63;
    const int row0 = blockIdx.x * 64;
    const int col0 = blockIdx.y * 128;

    const __bf16* a0 = Ag + (size_t)(row0 + (tid >> 2)) * ldA + (tid & 3) * 8;
    const __bf16* b0 = Bg + (size_t)(col0 + (tid >> 2)) * ldB + (tid & 3) * 8;
    __bf16* lA = As + wave * 512;
    __bf16* lB = Bs + wave * 512;

    const __bf16* Afrag = As + (lane & 15) * 32 + (lane >> 4) * 8;
    const __bf16* Bfrag = Bs + (wave * 32 + (lane & 15)) * 32 + (lane >> 4) * 8;

    floatx4 acc[4][2];
#pragma unroll
    for (int i = 0; i < 4; ++i)
#pragma unroll
        for (int j = 0; j < 2; ++j) acc[i][j] = (floatx4)0.0f;

    for (int kt = 0; kt < K / 32; ++kt) {
        const __bf16* ak = a0 + kt * 32;
        const __bf16* bk = b0 + kt * 32;
        async_copy16(ak,            lA);            // A: 64x32 in one copy
        async_copy16(bk,            lB);            // B: 128x32 in two copies
        async_copy16(bk + 64 * ldB, lB + 2048);
        __builtin_amdgcn_s_waitcnt(0);
        __syncthreads();

        bf16x8 af[4], bfr[2];
#pragma unroll
        for (int i = 0; i < 4; ++i) af[i] = *(const bf16x8*)(Afrag + i * 16 * 32);
#pragma unroll
        for (int j = 0; j < 2; ++j) bfr[j] = *(const bf16x8*)(Bfrag + j * 16 * 32);
#pragma unroll
        for (int i = 0; i < 4; ++i)
#pragma unroll
            for (int j = 0; j < 2; ++j)
                acc[i][j] = __builtin_amdgcn_mfma_f32_16x16x32_bf16(af[i], bfr[j], acc[i][j], 0, 0, 0);
        __syncthreads();
    }

    const int r0 = row0 + (lane >> 4) * 4;
    const int c0 = col0 + wave * 32 + (lane & 15);
#pragma unroll
    for (int i = 0; i < 4; ++i) {
#pragma unroll
        for (int j = 0; j < 2; ++j) {
            const int c = c0 + j * 16;
            const float aj = Adiag[c];
            const float hj = h2[c];
#pragma unroll
            for (int rg = 0; rg < 4; ++rg) {
                const int r = r0 + i * 16 + rg;
                out[(size_t)r * DZ + c] =
                    acc[i][j][rg] + aj * (float)zb[(size_t)r * DZ + c] + hj;
            }
        }
    }
}

// ---------------- launch ----------------

extern "C" void kernel_launch(void* const* d_in, const int* in_sizes, int n_in,
                              void* d_out, int out_size, void* d_ws, size_t ws_size,
                              hipStream_t stream) {
    const float* z  = (const float*)d_in[0];   // [8192,1024]
    const float* s  = (const float*)d_in[1];   // [8192,64]
    const float* A  = (const float*)d_in[2];   // [1024]
    const float* W1 = (const float*)d_in[3];   // [4096,1024]
    const float* W2 = (const float*)d_in[4];   // [1024,4096]
    const float* h1 = (const float*)d_in[5];   // [4096]
    const float* h2 = (const float*)d_in[6];   // [1024]
    const float* C  = (const float*)d_in[7];   // [1024,64]
    float* out = (float*)d_out;

    // workspace layout (bytes): Hb | zb | W1b | B2b  ~= 102 MB total
    char* ws = (char*)d_ws;
    size_t offHb  = 0;
    size_t offZb  = offHb  + (size_t)BB * KEXT * 2;      // 68,157,440
    size_t offW1b = offZb  + (size_t)BB * DZ * 2;        // +16,777,216
    size_t offB2b = offW1b + (size_t)DH * DZ * 2;        // +8,388,608
    __bf16* Hb  = (__bf16*)(ws + offHb);    // [8192 x 4160]: cols 0:4096 = relu(...), 4096:4160 = s
    __bf16* zb  = (__bf16*)(ws + offZb);    // [8192 x 1024]
    __bf16* W1b = (__bf16*)(ws + offW1b);   // [4096 x 1024]
    __bf16* B2b = (__bf16*)(ws + offB2b);   // [1024 x 4160] = [W2 | C]

    cvt_f32_bf16<<<(BB * DZ / 4 + 255) / 256, 256, 0, stream>>>(z, zb, BB * DZ / 4);
    cvt_f32_bf16<<<(DH * DZ / 4 + 255) / 256, 256, 0, stream>>>(W1, W1b, DH * DZ / 4);
    build_B2<<<DZ, 256, 0, stream>>>(W2, C, B2b);
    stage_s<<<BB * DS / 256, 256, 0, stream>>>(s, Hb);

    gemm1_relu<<<dim3(BB / 128, DH / 128), 256, 0, stream>>>(zb, W1b, h1, Hb);
    gemm2_out<<<dim3(BB / 64, DZ / 128), 256, 0, stream>>>(Hb, B2b, A, h2, zb, out);
}

// Round 4
// 282.159 us; speedup vs baseline: 1.0960x; 1.0960x over previous
//
#include <hip/hip_runtime.h>

// Problem constants (fixed shapes)
#define BB 8192      // batch
#define DZ 1024
#define DS 64
#define DH 4096
#define KEXT (DH + DS)   // 4160: K of GEMM2 = [H | s]

typedef float floatx4 __attribute__((ext_vector_type(4)));
typedef __bf16 bf16x8 __attribute__((ext_vector_type(8)));
typedef __attribute__((address_space(1))) void* as1_void_ptr;
typedef __attribute__((address_space(3))) void* as3_void_ptr;

__device__ __forceinline__ void async_copy16(const void* g, void* l) {
    // global -> LDS direct copy, 16B/lane; per-lane GLOBAL address,
    // wave-uniform LDS base + lane*16 dest.
    __builtin_amdgcn_global_load_lds((as1_void_ptr)g, (as3_void_ptr)l, 16, 0, 0);
}

// ---------------- merged prep kernel ----------------
// blocks [0,8192): z->zb        (8192*1024 f32, float4/thread)
// blocks [8192,12288): W1->W1b  (4096*1024 f32)
// blocks [12288,13312): B2b row build ([W2 | C])
// blocks [13312,15360): s -> Hb[:, 4096:4160]
__global__ void prep_all(const float* __restrict__ z, const float* __restrict__ W1,
                         const float* __restrict__ W2, const float* __restrict__ C,
                         const float* __restrict__ s,
                         __bf16* __restrict__ zb, __bf16* __restrict__ W1b,
                         __bf16* __restrict__ B2b, __bf16* __restrict__ Hb) {
    const int b = blockIdx.x, t = threadIdx.x;
    if (b < 8192) {
        int i = b * 256 + t;
        float4 v = ((const float4*)z)[i];
        __bf16* o = zb + (size_t)i * 4;
        o[0] = (__bf16)v.x; o[1] = (__bf16)v.y; o[2] = (__bf16)v.z; o[3] = (__bf16)v.w;
    } else if (b < 12288) {
        int i = (b - 8192) * 256 + t;
        float4 v = ((const float4*)W1)[i];
        __bf16* o = W1b + (size_t)i * 4;
        o[0] = (__bf16)v.x; o[1] = (__bf16)v.y; o[2] = (__bf16)v.z; o[3] = (__bf16)v.w;
    } else if (b < 13312) {
        int j = b - 12288;
        for (int h = t; h < KEXT; h += 256) {
            float v = (h < DH) ? W2[(size_t)j * DH + h] : C[(size_t)j * DS + (h - DH)];
            B2b[(size_t)j * KEXT + h] = (__bf16)v;
        }
    } else {
        int i = (b - 13312) * 256 + t;        // 0 .. 8192*64-1
        int r = i >> 6, k = i & 63;
        Hb[(size_t)r * KEXT + DH + k] = (__bf16)s[i];
    }
}

// ---------------- GEMM LDS layout ----------------
// Per operand: two back-to-back 128x32 panels (panel = K-half of BK=64),
// row stride 32 elem (64 B) -> verified m97 bank behavior.
// Staging: thread t (= wave*64+lane) loads global row row0 + (t>>2), col (t&3)*8;
// wave w's lanes land in LDS slab base + w*16*32 + lane*8 (16 rows x 32 cols).

// ---------------- GEMM1: Hb[:, :4096] = relu(zb @ W1b^T + h1) ----------------
// A = zb [8192 x 1024] K-major, B = W1b [4096 x 1024] K-major. BK=64, 16 iters.
__global__ __launch_bounds__(256) void gemm1_relu(
    const __bf16* __restrict__ Ag, const __bf16* __restrict__ Bg,
    const float* __restrict__ h1, __bf16* __restrict__ Hb)
{
    constexpr int ldA = DZ, ldB = DZ, KITER = DZ / 64;
    __shared__ __align__(16) __bf16 As[2 * 128 * 32];   // 16 KB (two panels)
    __shared__ __align__(16) __bf16 Bs[2 * 128 * 32];   // 16 KB

    const int tid = threadIdx.x;
    const int wave = tid >> 6, lane = tid & 63;
    const int wm = wave >> 1, wn = wave & 1;
    const int row0 = blockIdx.x * 128;
    const int col0 = blockIdx.y * 128;

    // per-lane global staging base: row = row0 + (tid>>2)  [includes wave!],
    // col = (tid&3)*8
    const __bf16* pA = Ag + (size_t)(row0 + (tid >> 2)) * ldA + (tid & 3) * 8;
    const __bf16* pB = Bg + (size_t)(col0 + (tid >> 2)) * ldB + (tid & 3) * 8;
    // wave-uniform LDS slab bases (lane*8 implicit in global_load_lds)
    __bf16* dA0 = As + wave * 16 * 32;
    __bf16* dB0 = Bs + wave * 16 * 32;

    const __bf16* Afrag = As + (wm * 64 + (lane & 15)) * 32 + (lane >> 4) * 8;
    const __bf16* Bfrag = Bs + (wn * 64 + (lane & 15)) * 32 + (lane >> 4) * 8;

    floatx4 acc[4][4];
#pragma unroll
    for (int i = 0; i < 4; ++i)
#pragma unroll
        for (int j = 0; j < 4; ++j) acc[i][j] = (floatx4)0.0f;

    for (int kt = 0; kt < KITER; ++kt) {
        const __bf16* ak = pA + kt * 64;
        const __bf16* bk = pB + kt * 64;
        // panel 0: K-cols [0,32); rows [0,64) then [64,128)
        async_copy16(ak,                         dA0);
        async_copy16(ak + (size_t)64 * ldA,      dA0 + 64 * 32);
        // panel 1: K-cols [32,64)
        async_copy16(ak + 32,                    dA0 + 128 * 32);
        async_copy16(ak + (size_t)64 * ldA + 32, dA0 + 128 * 32 + 64 * 32);
        async_copy16(bk,                         dB0);
        async_copy16(bk + (size_t)64 * ldB,      dB0 + 64 * 32);
        async_copy16(bk + 32,                    dB0 + 128 * 32);
        async_copy16(bk + (size_t)64 * ldB + 32, dB0 + 128 * 32 + 64 * 32);
        __builtin_amdgcn_s_waitcnt(0);
        __syncthreads();

#pragma unroll
        for (int ks = 0; ks < 2; ++ks) {
            bf16x8 af[4], bfr[4];
#pragma unroll
            for (int i = 0; i < 4; ++i) af[i] = *(const bf16x8*)(Afrag + ks * 4096 + i * 16 * 32);
#pragma unroll
            for (int j = 0; j < 4; ++j) bfr[j] = *(const bf16x8*)(Bfrag + ks * 4096 + j * 16 * 32);
#pragma unroll
            for (int i = 0; i < 4; ++i)
#pragma unroll
                for (int j = 0; j < 4; ++j)
                    acc[i][j] = __builtin_amdgcn_mfma_f32_16x16x32_bf16(af[i], bfr[j], acc[i][j], 0, 0, 0);
        }
        __syncthreads();
    }

    // epilogue: C/D layout col = lane&15, row = (lane>>4)*4 + reg
    const int r0 = row0 + wm * 64 + (lane >> 4) * 4;
    const int c0 = col0 + wn * 64 + (lane & 15);
#pragma unroll
    for (int i = 0; i < 4; ++i) {
#pragma unroll
        for (int j = 0; j < 4; ++j) {
            int c = c0 + j * 16;
            float bias = h1[c];
#pragma unroll
            for (int rg = 0; rg < 4; ++rg) {
                int r = r0 + i * 16 + rg;
                float v = acc[i][j][rg] + bias;
                v = v > 0.0f ? v : 0.0f;
                Hb[(size_t)r * KEXT + c] = (__bf16)v;
            }
        }
    }
}

// ---------------- GEMM2: out = Hb @ B2b^T + A*zb + h2 ----------------
// A = Hb [8192 x 4160] K-major, B = B2b [1024 x 4160] K-major. BK=64, 65 iters.
__global__ __launch_bounds__(256) void gemm2_out(
    const __bf16* __restrict__ Ag, const __bf16* __restrict__ Bg,
    const float* __restrict__ Adiag, const float* __restrict__ h2,
    const __bf16* __restrict__ zb, float* __restrict__ out)
{
    constexpr int ldA = KEXT, ldB = KEXT, KITER = KEXT / 64;
    __shared__ __align__(16) __bf16 As[2 * 128 * 32];
    __shared__ __align__(16) __bf16 Bs[2 * 128 * 32];

    const int tid = threadIdx.x;
    const int wave = tid >> 6, lane = tid & 63;
    const int wm = wave >> 1, wn = wave & 1;
    const int row0 = blockIdx.x * 128;
    const int col0 = blockIdx.y * 128;

    const __bf16* pA = Ag + (size_t)(row0 + (tid >> 2)) * ldA + (tid & 3) * 8;
    const __bf16* pB = Bg + (size_t)(col0 + (tid >> 2)) * ldB + (tid & 3) * 8;
    __bf16* dA0 = As + wave * 16 * 32;
    __bf16* dB0 = Bs + wave * 16 * 32;

    const __bf16* Afrag = As + (wm * 64 + (lane & 15)) * 32 + (lane >> 4) * 8;
    const __bf16* Bfrag = Bs + (wn * 64 + (lane & 15)) * 32 + (lane >> 4) * 8;

    floatx4 acc[4][4];
#pragma unroll
    for (int i = 0; i < 4; ++i)
#pragma unroll
        for (int j = 0; j < 4; ++j) acc[i][j] = (floatx4)0.0f;

    for (int kt = 0; kt < KITER; ++kt) {
        const __bf16* ak = pA + kt * 64;
        const __bf16* bk = pB + kt * 64;
        async_copy16(ak,                         dA0);
        async_copy16(ak + (size_t)64 * ldA,      dA0 + 64 * 32);
        async_copy16(ak + 32,                    dA0 + 128 * 32);
        async_copy16(ak + (size_t)64 * ldA + 32, dA0 + 128 * 32 + 64 * 32);
        async_copy16(bk,                         dB0);
        async_copy16(bk + (size_t)64 * ldB,      dB0 + 64 * 32);
        async_copy16(bk + 32,                    dB0 + 128 * 32);
        async_copy16(bk + (size_t)64 * ldB + 32, dB0 + 128 * 32 + 64 * 32);
        __builtin_amdgcn_s_waitcnt(0);
        __syncthreads();

#pragma unroll
        for (int ks = 0; ks < 2; ++ks) {
            bf16x8 af[4], bfr[4];
#pragma unroll
            for (int i = 0; i < 4; ++i) af[i] = *(const bf16x8*)(Afrag + ks * 4096 + i * 16 * 32);
#pragma unroll
            for (int j = 0; j < 4; ++j) bfr[j] = *(const bf16x8*)(Bfrag + ks * 4096 + j * 16 * 32);
#pragma unroll
            for (int i = 0; i < 4; ++i)
#pragma unroll
                for (int j = 0; j < 4; ++j)
                    acc[i][j] = __builtin_amdgcn_mfma_f32_16x16x32_bf16(af[i], bfr[j], acc[i][j], 0, 0, 0);
        }
        __syncthreads();
    }

    const int r0 = row0 + wm * 64 + (lane >> 4) * 4;
    const int c0 = col0 + wn * 64 + (lane & 15);
#pragma unroll
    for (int i = 0; i < 4; ++i) {
#pragma unroll
        for (int j = 0; j < 4; ++j) {
            const int c = c0 + j * 16;
            const float aj = Adiag[c];
            const float hj = h2[c];
#pragma unroll
            for (int rg = 0; rg < 4; ++rg) {
                const int r = r0 + i * 16 + rg;
                out[(size_t)r * DZ + c] =
                    acc[i][j][rg] + aj * (float)zb[(size_t)r * DZ + c] + hj;
            }
        }
    }
}

// ---------------- launch ----------------

extern "C" void kernel_launch(void* const* d_in, const int* in_sizes, int n_in,
                              void* d_out, int out_size, void* d_ws, size_t ws_size,
                              hipStream_t stream) {
    const float* z  = (const float*)d_in[0];   // [8192,1024]
    const float* s  = (const float*)d_in[1];   // [8192,64]
    const float* A  = (const float*)d_in[2];   // [1024]
    const float* W1 = (const float*)d_in[3];   // [4096,1024]
    const float* W2 = (const float*)d_in[4];   // [1024,4096]
    const float* h1 = (const float*)d_in[5];   // [4096]
    const float* h2 = (const float*)d_in[6];   // [1024]
    const float* C  = (const float*)d_in[7];   // [1024,64]
    float* out = (float*)d_out;

    // workspace layout (bytes): Hb | zb | W1b | B2b  ~= 102 MB total
    char* ws = (char*)d_ws;
    size_t offHb  = 0;
    size_t offZb  = offHb  + (size_t)BB * KEXT * 2;      // 68,157,440
    size_t offW1b = offZb  + (size_t)BB * DZ * 2;        // +16,777,216
    size_t offB2b = offW1b + (size_t)DH * DZ * 2;        // +8,388,608
    __bf16* Hb  = (__bf16*)(ws + offHb);    // [8192 x 4160]: cols 0:4096 = relu(...), 4096:4160 = s
    __bf16* zb  = (__bf16*)(ws + offZb);    // [8192 x 1024]
    __bf16* W1b = (__bf16*)(ws + offW1b);   // [4096 x 1024]
    __bf16* B2b = (__bf16*)(ws + offB2b);   // [1024 x 4160] = [W2 | C]

    prep_all<<<15360, 256, 0, stream>>>(z, W1, W2, C, s, zb, W1b, B2b, Hb);
    gemm1_relu<<<dim3(BB / 128, DH / 128), 256, 0, stream>>>(zb, W1b, h1, Hb);
    gemm2_out<<<dim3(BB / 128, DZ / 128), 256, 0, stream>>>(Hb, B2b, A, h2, zb, out);
}